// Round 17
// baseline (197.265 us; speedup 1.0000x reference)
//
#include <hip/hip_runtime.h>
#include <hip/hip_bf16.h>

#define NH 16
#define NKV 4
#define HD 128
// ATT_SCALE * log2(e): Q pre-scaled so P = exp2(S_mfma)
#define QSCALE 0.1275174272f

using bf16x8 = __attribute__((ext_vector_type(8))) __bf16;
using f32x4  = __attribute__((ext_vector_type(4))) float;
using u16x8  = __attribute__((ext_vector_type(8))) unsigned short;
using u16x4  = __attribute__((ext_vector_type(4))) unsigned short;
using u16x2  = __attribute__((ext_vector_type(2))) unsigned short;

__device__ __forceinline__ unsigned short f2b(float f) {
  __hip_bfloat16 h = __float2bfloat16(f);
  return __builtin_bit_cast(unsigned short, h);
}
__device__ __forceinline__ float b2f(unsigned short u) {
  unsigned int v = ((unsigned int)u) << 16;
  return __builtin_bit_cast(float, v);
}

__device__ __forceinline__ void glds16(const unsigned short* g, unsigned short* l) {
  __builtin_amdgcn_global_load_lds(
      (const __attribute__((address_space(1))) unsigned int*)(const void*)g,
      (__attribute__((address_space(3))) unsigned int*)(void*)l, 16, 0, 0);
}

// ---------------- fused fp32 -> bf16 conversion + cos/sin table -----------
__global__ __launch_bounds__(256) void cvt_fused(const float* __restrict__ x,
                                                 const float* __restrict__ wq,
                                                 const float* __restrict__ wk,
                                                 const float* __restrict__ wv,
                                                 const float* __restrict__ wo,
                                                 const float* __restrict__ freqs,
                                                 unsigned short* __restrict__ xb,
                                                 unsigned short* __restrict__ wqkvb,
                                                 unsigned short* __restrict__ wob,
                                                 float2* __restrict__ cs_tab) {
  int i = blockIdx.x * 256 + threadIdx.x;
  if (i >= 2359296) {                // cos/sin table: 2048*64 angles
    int k = i - 2359296;
    float f = freqs[k];
    float2 cs; cs.x = cosf(f); cs.y = sinf(f);
    cs_tab[k] = cs;
    return;
  }
  const float* src;
  unsigned short* dst;
  int off;
  if (i < 1048576)      { src = x;  dst = xb;              off = i; }
  else if (i < 1572864) { src = wq; dst = wqkvb;           off = i - 1048576; }
  else if (i < 1703936) { src = wk; dst = wqkvb + 4194304; off = i - 1572864; }
  else if (i < 1835008) { src = wv; dst = wqkvb + 5242880; off = i - 1703936; }
  else                  { src = wo; dst = wob;             off = i - 1835008; }
  const float4* s4 = reinterpret_cast<const float4*>(src) + (size_t)off * 2;
  float4 v0 = s4[0], v1 = s4[1];
  u16x8 o;
  o[0] = f2b(v0.x); o[1] = f2b(v0.y); o[2] = f2b(v0.z); o[3] = f2b(v0.w);
  o[4] = f2b(v1.x); o[5] = f2b(v1.y); o[6] = f2b(v1.z); o[7] = f2b(v1.w);
  reinterpret_cast<u16x8*>(dst)[off] = o;
}

// ======================= m97-geometry GEMM core ============================
#define GEMM97_PREAMBLE(Kvar)                                                  \
  const int tid = threadIdx.x, lane = tid & 63;                                \
  const int wid = tid >> 6, wm = wid >> 1, wn = wid & 1;                       \
  const int cpx = gridDim.x >> 3;                                              \
  const int wgid = (blockIdx.x & 7) * cpx + (blockIdx.x >> 3);                 \
  const int bx = wgid % nbx, by = wgid / nbx;                                  \
  const int row0 = by * 128, col0 = bx * 128;                                  \
  const int fr = lane & 15, g = lane >> 4;                                     \
  const int NT = (Kvar) >> 5;                                                  \
  size_t offA[2], offB[2];                                                     \
  _Pragma("unroll")                                                            \
  for (int l = 0; l < 2; l++) {                                                \
    int cid = tid + l * 256, R = cid >> 3, phys = cid & 7, cl = phys ^ (R & 7);\
    offA[l] = (size_t)(row0 + 2 * R + (cl >> 2)) * (Kvar) + (cl & 3) * 8;      \
    offB[l] = (size_t)(col0 + 2 * R + (cl >> 2)) * (Kvar) + (cl & 3) * 8;      \
  }

__device__ __forceinline__ bf16x8 ldfrag97(const unsigned short* buf, int row, int g) {
  int R = row >> 1;
  int phys = ((((row & 1) << 2) | g) ^ (R & 7));
  return *reinterpret_cast<const bf16x8*>(&buf[R * 64 + phys * 8]);
}

// ---------------- QKV GEMM (m97 core) + fused RoPE/V-transpose epilogue ---
__global__ __launch_bounds__(256, 3) void gemm_qkv(const unsigned short* __restrict__ A,
                                                   const unsigned short* __restrict__ B,
                                                   const float2* __restrict__ cs_tab,
                                                   unsigned short* __restrict__ qro,
                                                   unsigned short* __restrict__ kro,
                                                   unsigned short* __restrict__ vt,
                                                   float* __restrict__ newk,
                                                   float* __restrict__ newv,
                                                   int K, int nbx) {
  __shared__ unsigned short As[2][128 * 32];
  __shared__ unsigned short Bs[2][128 * 32];
  GEMM97_PREAMBLE(K)

  auto stage = [&](int t, int sb) {
    int k0 = t * 32;
#pragma unroll
    for (int l = 0; l < 2; l++) {
      glds16(A + offA[l] + k0, &As[sb][(tid + l * 256) * 8]);
      glds16(B + offB[l] + k0, &Bs[sb][(tid + l * 256) * 8]);
    }
  };

  f32x4 acc[4][4];
#pragma unroll
  for (int i = 0; i < 4; i++)
#pragma unroll
    for (int j = 0; j < 4; j++) acc[i][j] = f32x4{0.f, 0.f, 0.f, 0.f};

  stage(0, 0);
  int buf = 0;
#pragma unroll 1
  for (int t = 0; t < NT; ++t) {
    __syncthreads();
    if (t + 1 < NT) stage(t + 1, buf ^ 1);
    bf16x8 af[4], bfr[4];
#pragma unroll
    for (int mf = 0; mf < 4; mf++) af[mf] = ldfrag97(As[buf], wm * 64 + mf * 16 + fr, g);
#pragma unroll
    for (int nf = 0; nf < 4; nf++) bfr[nf] = ldfrag97(Bs[buf], wn * 64 + nf * 16 + fr, g);
    __builtin_amdgcn_s_setprio(1);
#pragma unroll
    for (int mf = 0; mf < 4; mf++)
#pragma unroll
      for (int nf = 0; nf < 4; nf++)
        acc[mf][nf] = __builtin_amdgcn_mfma_f32_16x16x32_bf16(af[mf], bfr[nf], acc[mf][nf], 0, 0, 0);
    __builtin_amdgcn_s_setprio(0);
    buf ^= 1;
  }

  // ---- fused epilogue: RoPE(Q,K) + K/V f32 outputs + V transpose ----
#pragma unroll
  for (int i = 0; i < 4; i++) {
    int rbase = row0 + wm * 64 + i * 16 + g * 4;
    int bb = rbase >> 11;
    int sr0 = rbase & 2047;
#pragma unroll
    for (int j = 0; j < 4; j++) {
      int cb = col0 + wn * 64 + j * 16 + fr;
      int d = cb & 127;
      if (cb < 2048) {                           // Q + RoPE (pre-scaled)
        int hq = cb >> 7;
        unsigned short* qp = qro + ((size_t)(bb * 16 + hq) * 2048 + sr0) * 128 + d;
#pragma unroll
        for (int r = 0; r < 4; r++) {
          float own = acc[i][j][r];
          float par = __shfl_xor(own, 1);
          float2 cs = cs_tab[(sr0 + r) * 64 + (d >> 1)];
          float o = (fr & 1) ? (par * cs.y + own * cs.x) : (own * cs.x - par * cs.y);
          qp[(size_t)r * 128] = f2b(o * QSCALE);
        }
      } else if (cb < 2560) {                    // K + RoPE + newk f32
        int kvh = (cb >> 7) & 3;
        unsigned short* kp = kro + ((size_t)(bb * 4 + kvh) * 2048 + sr0) * 128 + d;
        float* nk = newk + ((size_t)bb * 2048 + sr0) * 512 + kvh * 128 + d;
#pragma unroll
        for (int r = 0; r < 4; r++) {
          float own = acc[i][j][r];
          float par = __shfl_xor(own, 1);
          float2 cs = cs_tab[(sr0 + r) * 64 + (d >> 1)];
          float o = (fr & 1) ? (par * cs.y + own * cs.x) : (own * cs.x - par * cs.y);
          kp[(size_t)r * 128] = f2b(o);
          nk[(size_t)r * 512] = o;
        }
      } else {                                   // V: newv f32 + vt slot-permuted
        int kvh = (cb >> 7) & 3;
        float* nv = newv + ((size_t)bb * 2048 + sr0) * 512 + kvh * 128 + d;
        u16x4 pack;
#pragma unroll
        for (int r = 0; r < 4; r++) {
          float v = acc[i][j][r];
          nv[(size_t)r * 512] = v;
          pack[r] = f2b(v);
        }
        int kl = sr0 & 31;                       // multiple of 4
        int slotb = ((kl >> 2) & 3) * 8 + (kl >> 4) * 4;
        *reinterpret_cast<u16x4*>(vt + ((size_t)(bb * 4 + kvh) * 128 + d) * 2048
                                  + (sr0 & ~31) + slotb) = pack;
      }
    }
  }
}

// ---------------- O-projection GEMM (m97 core, f32 out) --------------------
__global__ __launch_bounds__(256, 3) void gemm_o(const unsigned short* __restrict__ A,
                                                 const unsigned short* __restrict__ B,
                                                 float* __restrict__ C,
                                                 int N, int K, int nbx) {
  __shared__ unsigned short As[2][128 * 32];
  __shared__ unsigned short Bs[2][128 * 32];
  GEMM97_PREAMBLE(K)

  auto stage = [&](int t, int sb) {
    int k0 = t * 32;
#pragma unroll
    for (int l = 0; l < 2; l++) {
      glds16(A + offA[l] + k0, &As[sb][(tid + l * 256) * 8]);
      glds16(B + offB[l] + k0, &Bs[sb][(tid + l * 256) * 8]);
    }
  };

  f32x4 acc[4][4];
#pragma unroll
  for (int i = 0; i < 4; i++)
#pragma unroll
    for (int j = 0; j < 4; j++) acc[i][j] = f32x4{0.f, 0.f, 0.f, 0.f};

  stage(0, 0);
  int buf = 0;
#pragma unroll 1
  for (int t = 0; t < NT; ++t) {
    __syncthreads();
    if (t + 1 < NT) stage(t + 1, buf ^ 1);
    bf16x8 af[4], bfr[4];
#pragma unroll
    for (int mf = 0; mf < 4; mf++) af[mf] = ldfrag97(As[buf], wm * 64 + mf * 16 + fr, g);
#pragma unroll
    for (int nf = 0; nf < 4; nf++) bfr[nf] = ldfrag97(Bs[buf], wn * 64 + nf * 16 + fr, g);
    __builtin_amdgcn_s_setprio(1);
#pragma unroll
    for (int mf = 0; mf < 4; mf++)
#pragma unroll
      for (int nf = 0; nf < 4; nf++)
        acc[mf][nf] = __builtin_amdgcn_mfma_f32_16x16x32_bf16(af[mf], bfr[nf], acc[mf][nf], 0, 0, 0);
    __builtin_amdgcn_s_setprio(0);
    buf ^= 1;
  }

#pragma unroll
  for (int i = 0; i < 4; i++) {
#pragma unroll
    for (int j = 0; j < 4; j++) {
      int rbase = row0 + wm * 64 + i * 16 + g * 4;
      int cb = col0 + wn * 64 + j * 16 + fr;
#pragma unroll
      for (int r = 0; r < 4; r++)
        C[(size_t)(rbase + r) * N + cb] = acc[i][j][r];
    }
  }
}

// ---------------- flash attention: wave = (head-pair, q16-subtile) --------
// Block = 4 waves = 2 head-pairs x 2 q16-subtiles -> q32 x 4 heads per block.
// Each wave computes 2 heads against ONE set of K/V fragment reads (16 KB
// feeds 34 MFMA vs 17 before: LDS-read traffic per MFMA halved). Both heads
// share q-rows -> identical causal mask. 3 blocks/CU (VGPR-capped).
__global__ __launch_bounds__(256, 3) void attn_kernel(const unsigned short* __restrict__ qro,
                                                      const unsigned short* __restrict__ kro,
                                                      const unsigned short* __restrict__ vt,
                                                      unsigned short* __restrict__ out) {
  __shared__ unsigned short Ks[2][32 * 128];   // [kv][d], rows 256B, swizzled
  __shared__ unsigned short Vs[2][64 * 64];    // paired-d rows 128B, swizzled
  const int tid = threadIdx.x, lane = tid & 63, w = tid >> 6;
  const int kvhb = blockIdx.x & 7;             // XCD pin
  const int kvh = kvhb & 3, b = kvhb >> 2;
  const int s = blockIdx.x >> 3;               // 0..63
  const int T = (s < 32) ? s : (95 - s);       // mirrored pairs {T, 63-T}
  const int sub = w >> 1, hp = w & 1;
  const int h0 = kvh * 4 + hp * 2;             // wave = 2 heads
  const int qbase = T * 32 + sub * 16;
  const int fr = lane & 15, g = lane >> 4, fk = g * 8;
  const unsigned short* Kp = kro + (size_t)(b * 4 + kvh) * 2048 * 128;
  const unsigned short* Vtp = vt + (size_t)(b * 4 + kvh) * 128 * 2048;
  const unsigned short* Qp0 = qro + ((size_t)(b * 16 + h0) * 2048 + qbase) * 128;
  const unsigned short* Qp1 = qro + ((size_t)(b * 16 + h0 + 1) * 2048 + qbase) * 128;

  bf16x8 qf0[4], qf1[4];
#pragma unroll
  for (int kk = 0; kk < 4; kk++) {
    qf0[kk] = *reinterpret_cast<const bf16x8*>(Qp0 + fr * 128 + kk * 32 + fk);
    qf1[kk] = *reinterpret_cast<const bf16x8*>(Qp1 + fr * 128 + kk * 32 + fk);
  }

  u16x8 onesu;
#pragma unroll
  for (int j = 0; j < 8; j++) onesu[j] = 0x3F80;  // bf16 1.0
  bf16x8 ones = __builtin_bit_cast(bf16x8, onesu);

  f32x4 o0[8], o1[8];
#pragma unroll
  for (int dt = 0; dt < 8; dt++) { o0[dt] = f32x4{0.f,0.f,0.f,0.f}; o1[dt] = f32x4{0.f,0.f,0.f,0.f}; }
  f32x4 dacc0 = f32x4{0.f,0.f,0.f,0.f};
  f32x4 dacc1 = f32x4{0.f,0.f,0.f,0.f};
  const int qrow_s = qbase + fr;
  const int niter = T + 1;

  // stage (256 thr, 4 waves): K 8 KB + V 8 KB per 32-KV tile
  const int krow = w * 8 + (lane >> 4);        // K stage rows (+j*4)
  const int kcol = lane & 15;
  const int vrow = w * 16 + (lane >> 3);       // V stage rows, paired-d (+j*8)
  const int vcol = lane & 7;

  auto stage = [&](int kv0, int buf) {
    unsigned short* Kb = &Ks[buf][0];
    unsigned short* Vb = &Vs[buf][0];
#pragma unroll
    for (int j = 0; j < 2; j++) {
      int r = krow + j * 4;
      glds16(Kp + (size_t)(kv0 + r) * 128 + ((kcol ^ (r & 7)) * 8),
             Kb + (w * 8 + j * 4) * 128);
    }
#pragma unroll
    for (int j = 0; j < 2; j++) {
      int r = vrow + j * 8;
      int u = vcol ^ (r & 7);
      int d = 2 * r + (u >> 2);
      glds16(Vtp + (size_t)d * 2048 + kv0 + (u & 3) * 8,
             Vb + (w * 16 + j * 8) * 64);
    }
  };

  auto step = [&](int kv0, bool mask, int buf) {
    const unsigned short* Kb = &Ks[buf][0];
    const unsigned short* Vb = &Vs[buf][0];
    f32x4 sc0[2], sc1[2];                      // [head][kv-half]
    sc0[0] = sc0[1] = f32x4{0.f,0.f,0.f,0.f};
    sc1[0] = sc1[1] = f32x4{0.f,0.f,0.f,0.f};
    __builtin_amdgcn_s_setprio(1);
#pragma unroll
    for (int kk = 0; kk < 4; kk++) {
      int blk = ((kk * 4 + g) ^ (fr & 7)) * 8;
      bf16x8 ka0 = *reinterpret_cast<const bf16x8*>(Kb + (fr +  0) * 128 + blk);
      bf16x8 ka1 = *reinterpret_cast<const bf16x8*>(Kb + (fr + 16) * 128 + blk);
      sc0[0] = __builtin_amdgcn_mfma_f32_16x16x32_bf16(ka0, qf0[kk], sc0[0], 0, 0, 0);
      sc1[0] = __builtin_amdgcn_mfma_f32_16x16x32_bf16(ka0, qf1[kk], sc1[0], 0, 0, 0);
      sc0[1] = __builtin_amdgcn_mfma_f32_16x16x32_bf16(ka1, qf0[kk], sc0[1], 0, 0, 0);
      sc1[1] = __builtin_amdgcn_mfma_f32_16x16x32_bf16(ka1, qf1[kk], sc1[1], 0, 0, 0);
    }
    __builtin_amdgcn_s_setprio(0);
#pragma unroll
    for (int ss = 0; ss < 2; ss++)
#pragma unroll
      for (int r = 0; r < 4; r++) {
        bool m = mask && (kv0 + 16 * ss + 4 * g + r > qrow_s);  // same for both heads
        float v0 = m ? -1e30f : sc0[ss][r];
        float v1 = m ? -1e30f : sc1[ss][r];
        sc0[ss][r] = __builtin_amdgcn_exp2f(v0);
        sc1[ss][r] = __builtin_amdgcn_exp2f(v1);
      }
    u16x8 pau, pbu;
#pragma unroll
    for (int j = 0; j < 4; j++) {
      pau[j]     = f2b(sc0[0][j]);
      pau[4 + j] = f2b(sc0[1][j]);
      pbu[j]     = f2b(sc1[0][j]);
      pbu[4 + j] = f2b(sc1[1][j]);
    }
    bf16x8 pa = __builtin_bit_cast(bf16x8, pau);
    bf16x8 pb = __builtin_bit_cast(bf16x8, pbu);
    dacc0 = __builtin_amdgcn_mfma_f32_16x16x32_bf16(pa, ones, dacc0, 0, 0, 0);
    dacc1 = __builtin_amdgcn_mfma_f32_16x16x32_bf16(pb, ones, dacc1, 0, 0, 0);
    __builtin_amdgcn_s_setprio(1);
#pragma unroll
    for (int dt = 0; dt < 8; dt++) {
      int jr = dt * 8 + (fr >> 1);
      int c = ((fr & 1) * 4 + g) ^ (fr >> 1);
      bf16x8 vf = *reinterpret_cast<const bf16x8*>(Vb + jr * 64 + c * 8);
      o0[dt] = __builtin_amdgcn_mfma_f32_16x16x32_bf16(pa, vf, o0[dt], 0, 0, 0);
      o1[dt] = __builtin_amdgcn_mfma_f32_16x16x32_bf16(pb, vf, o1[dt], 0, 0, 0);
    }
    __builtin_amdgcn_s_setprio(0);
  };

  stage(0, 0);
  int buf = 0;
  for (int i = 0; i < niter; i++) {
    __syncthreads();
    if (i + 1 < niter) stage((i + 1) * 32, buf ^ 1);
    step(i * 32, i == niter - 1, buf);
    buf ^= 1;
  }

#pragma unroll
  for (int r = 0; r < 4; r++) {
    float inv0 = 1.0f / dacc0[r];
    float inv1 = 1.0f / dacc1[r];
    int qrow = qbase + g * 4 + r;
    size_t ro0 = ((size_t)b * 2048 + qrow) * 2048 + (size_t)h0 * 128;
#pragma unroll
    for (int dt = 0; dt < 8; dt++) {
      out[ro0 + dt * 16 + fr]       = f2b(o0[dt][r] * inv0);
      out[ro0 + 128 + dt * 16 + fr] = f2b(o1[dt][r] * inv1);
    }
  }
}

// ---------------- launch ---------------------------------------------------
extern "C" void kernel_launch(void* const* d_in, const int* in_sizes, int n_in,
                              void* d_out, int out_size, void* d_ws, size_t ws_size,
                              hipStream_t stream) {
  const float* x  = (const float*)d_in[0];
  const float* wq = (const float*)d_in[1];
  const float* wk = (const float*)d_in[2];
  const float* wv = (const float*)d_in[3];
  const float* wo = (const float*)d_in[4];
  const float* freqs = (const float*)d_in[5];

  char* ws = (char*)d_ws;
  unsigned short* xb    = (unsigned short*)(ws);             // 16 MB, reused as attn out
  unsigned short* attn  = xb;
  unsigned short* wqkvb = (unsigned short*)(ws + 16777216);  // [3072][2048] bf16
  unsigned short* wob   = (unsigned short*)(ws + 29360128);
  float2*         cstab = (float2*)(ws + 37748736);          // [2048][64] cos/sin, 1 MB
  unsigned short* qro   = (unsigned short*)(ws + 62914560);
  unsigned short* kro   = (unsigned short*)(ws + 79691776);
  unsigned short* vt    = (unsigned short*)(ws + 83886080);

  float* out_o = (float*)d_out;
  float* out_k = (float*)d_out + 8388608;
  float* out_v = (float*)d_out + 10485760;

  cvt_fused<<<9728, 256, 0, stream>>>(x, wq, wk, wv, wo, freqs, xb, wqkvb, wob, cstab);

  // QKV (m97 core + fused RoPE/vt): 128x128 tiles -> 32x24 = 768 blocks = 3/CU
  gemm_qkv<<<768, 256, 0, stream>>>(xb, wqkvb, cstab, qro, kro, vt, out_k, out_v, 2048, 24);

  // attn: 64 q32-tiles x 8 (kvh,b) = 512 blocks of 4 waves (2 heads/wave), 3/CU
  attn_kernel<<<512, 256, 0, stream>>>(qro, kro, vt, attn);

  // O: 128x128 tiles -> 32x16 = 512 blocks = 2/CU
  gemm_o<<<512, 256, 0, stream>>>(attn, wob, out_o, 2048, 2048, 16);
}

// Round 18
// 186.988 us; speedup vs baseline: 1.0550x; 1.0550x over previous
//
#include <hip/hip_runtime.h>
#include <hip/hip_bf16.h>

#define NH 16
#define NKV 4
#define HD 128
// ATT_SCALE * log2(e): Q pre-scaled so P = exp2(S_mfma)
#define QSCALE 0.1275174272f

using bf16x8 = __attribute__((ext_vector_type(8))) __bf16;
using f32x4  = __attribute__((ext_vector_type(4))) float;
using u16x8  = __attribute__((ext_vector_type(8))) unsigned short;
using u16x4  = __attribute__((ext_vector_type(4))) unsigned short;
using u16x2  = __attribute__((ext_vector_type(2))) unsigned short;

__device__ __forceinline__ unsigned short f2b(float f) {
  __hip_bfloat16 h = __float2bfloat16(f);
  return __builtin_bit_cast(unsigned short, h);
}
__device__ __forceinline__ float b2f(unsigned short u) {
  unsigned int v = ((unsigned int)u) << 16;
  return __builtin_bit_cast(float, v);
}

__device__ __forceinline__ void glds16(const unsigned short* g, unsigned short* l) {
  __builtin_amdgcn_global_load_lds(
      (const __attribute__((address_space(1))) unsigned int*)(const void*)g,
      (__attribute__((address_space(3))) unsigned int*)(void*)l, 16, 0, 0);
}

// ---------------- fused fp32 -> bf16 conversion + cos/sin table -----------
__global__ __launch_bounds__(256) void cvt_fused(const float* __restrict__ x,
                                                 const float* __restrict__ wq,
                                                 const float* __restrict__ wk,
                                                 const float* __restrict__ wv,
                                                 const float* __restrict__ wo,
                                                 const float* __restrict__ freqs,
                                                 unsigned short* __restrict__ xb,
                                                 unsigned short* __restrict__ wqkvb,
                                                 unsigned short* __restrict__ wob,
                                                 float2* __restrict__ cs_tab) {
  int i = blockIdx.x * 256 + threadIdx.x;
  if (i >= 2359296) {                // cos/sin table: 2048*64 angles
    int k = i - 2359296;
    float f = freqs[k];
    float2 cs; cs.x = cosf(f); cs.y = sinf(f);
    cs_tab[k] = cs;
    return;
  }
  const float* src;
  unsigned short* dst;
  int off;
  if (i < 1048576)      { src = x;  dst = xb;              off = i; }
  else if (i < 1572864) { src = wq; dst = wqkvb;           off = i - 1048576; }
  else if (i < 1703936) { src = wk; dst = wqkvb + 4194304; off = i - 1572864; }
  else if (i < 1835008) { src = wv; dst = wqkvb + 5242880; off = i - 1703936; }
  else                  { src = wo; dst = wob;             off = i - 1835008; }
  const float4* s4 = reinterpret_cast<const float4*>(src) + (size_t)off * 2;
  float4 v0 = s4[0], v1 = s4[1];
  u16x8 o;
  o[0] = f2b(v0.x); o[1] = f2b(v0.y); o[2] = f2b(v0.z); o[3] = f2b(v0.w);
  o[4] = f2b(v1.x); o[5] = f2b(v1.y); o[6] = f2b(v1.z); o[7] = f2b(v1.w);
  reinterpret_cast<u16x8*>(dst)[off] = o;
}

// ======================= m97-geometry GEMM core ============================
#define GEMM97_PREAMBLE(Kvar)                                                  \
  const int tid = threadIdx.x, lane = tid & 63;                                \
  const int wid = tid >> 6, wm = wid >> 1, wn = wid & 1;                       \
  const int cpx = gridDim.x >> 3;                                              \
  const int wgid = (blockIdx.x & 7) * cpx + (blockIdx.x >> 3);                 \
  const int bx = wgid % nbx, by = wgid / nbx;                                  \
  const int row0 = by * 128, col0 = bx * 128;                                  \
  const int fr = lane & 15, g = lane >> 4;                                     \
  const int NT = (Kvar) >> 5;                                                  \
  size_t offA[2], offB[2];                                                     \
  _Pragma("unroll")                                                            \
  for (int l = 0; l < 2; l++) {                                                \
    int cid = tid + l * 256, R = cid >> 3, phys = cid & 7, cl = phys ^ (R & 7);\
    offA[l] = (size_t)(row0 + 2 * R + (cl >> 2)) * (Kvar) + (cl & 3) * 8;      \
    offB[l] = (size_t)(col0 + 2 * R + (cl >> 2)) * (Kvar) + (cl & 3) * 8;      \
  }

__device__ __forceinline__ bf16x8 ldfrag97(const unsigned short* buf, int row, int g) {
  int R = row >> 1;
  int phys = ((((row & 1) << 2) | g) ^ (R & 7));
  return *reinterpret_cast<const bf16x8*>(&buf[R * 64 + phys * 8]);
}

// ---------------- QKV GEMM (m97 core) + fused RoPE/V-transpose epilogue ---
__global__ __launch_bounds__(256, 3) void gemm_qkv(const unsigned short* __restrict__ A,
                                                   const unsigned short* __restrict__ B,
                                                   const float2* __restrict__ cs_tab,
                                                   unsigned short* __restrict__ qro,
                                                   unsigned short* __restrict__ kro,
                                                   unsigned short* __restrict__ vt,
                                                   float* __restrict__ newk,
                                                   float* __restrict__ newv,
                                                   int K, int nbx) {
  __shared__ unsigned short As[2][128 * 32];
  __shared__ unsigned short Bs[2][128 * 32];
  GEMM97_PREAMBLE(K)

  auto stage = [&](int t, int sb) {
    int k0 = t * 32;
#pragma unroll
    for (int l = 0; l < 2; l++) {
      glds16(A + offA[l] + k0, &As[sb][(tid + l * 256) * 8]);
      glds16(B + offB[l] + k0, &Bs[sb][(tid + l * 256) * 8]);
    }
  };

  f32x4 acc[4][4];
#pragma unroll
  for (int i = 0; i < 4; i++)
#pragma unroll
    for (int j = 0; j < 4; j++) acc[i][j] = f32x4{0.f, 0.f, 0.f, 0.f};

  stage(0, 0);
  int buf = 0;
#pragma unroll 1
  for (int t = 0; t < NT; ++t) {
    __syncthreads();
    if (t + 1 < NT) stage(t + 1, buf ^ 1);
    bf16x8 af[4], bfr[4];
#pragma unroll
    for (int mf = 0; mf < 4; mf++) af[mf] = ldfrag97(As[buf], wm * 64 + mf * 16 + fr, g);
#pragma unroll
    for (int nf = 0; nf < 4; nf++) bfr[nf] = ldfrag97(Bs[buf], wn * 64 + nf * 16 + fr, g);
    __builtin_amdgcn_s_setprio(1);
#pragma unroll
    for (int mf = 0; mf < 4; mf++)
#pragma unroll
      for (int nf = 0; nf < 4; nf++)
        acc[mf][nf] = __builtin_amdgcn_mfma_f32_16x16x32_bf16(af[mf], bfr[nf], acc[mf][nf], 0, 0, 0);
    __builtin_amdgcn_s_setprio(0);
    buf ^= 1;
  }

  // ---- fused epilogue: RoPE(Q,K) + K/V f32 outputs + V transpose ----
#pragma unroll
  for (int i = 0; i < 4; i++) {
    int rbase = row0 + wm * 64 + i * 16 + g * 4;
    int bb = rbase >> 11;
    int sr0 = rbase & 2047;
#pragma unroll
    for (int j = 0; j < 4; j++) {
      int cb = col0 + wn * 64 + j * 16 + fr;
      int d = cb & 127;
      if (cb < 2048) {                           // Q + RoPE (pre-scaled)
        int hq = cb >> 7;
        unsigned short* qp = qro + ((size_t)(bb * 16 + hq) * 2048 + sr0) * 128 + d;
#pragma unroll
        for (int r = 0; r < 4; r++) {
          float own = acc[i][j][r];
          float par = __shfl_xor(own, 1);
          float2 cs = cs_tab[(sr0 + r) * 64 + (d >> 1)];
          float o = (fr & 1) ? (par * cs.y + own * cs.x) : (own * cs.x - par * cs.y);
          qp[(size_t)r * 128] = f2b(o * QSCALE);
        }
      } else if (cb < 2560) {                    // K + RoPE + newk f32
        int kvh = (cb >> 7) & 3;
        unsigned short* kp = kro + ((size_t)(bb * 4 + kvh) * 2048 + sr0) * 128 + d;
        float* nk = newk + ((size_t)bb * 2048 + sr0) * 512 + kvh * 128 + d;
#pragma unroll
        for (int r = 0; r < 4; r++) {
          float own = acc[i][j][r];
          float par = __shfl_xor(own, 1);
          float2 cs = cs_tab[(sr0 + r) * 64 + (d >> 1)];
          float o = (fr & 1) ? (par * cs.y + own * cs.x) : (own * cs.x - par * cs.y);
          kp[(size_t)r * 128] = f2b(o);
          nk[(size_t)r * 512] = o;
        }
      } else {                                   // V: newv f32 + vt slot-permuted
        int kvh = (cb >> 7) & 3;
        float* nv = newv + ((size_t)bb * 2048 + sr0) * 512 + kvh * 128 + d;
        u16x4 pack;
#pragma unroll
        for (int r = 0; r < 4; r++) {
          float v = acc[i][j][r];
          nv[(size_t)r * 512] = v;
          pack[r] = f2b(v);
        }
        int kl = sr0 & 31;                       // multiple of 4
        int slotb = ((kl >> 2) & 3) * 8 + (kl >> 4) * 4;
        *reinterpret_cast<u16x4*>(vt + ((size_t)(bb * 4 + kvh) * 128 + d) * 2048
                                  + (sr0 & ~31) + slotb) = pack;
      }
    }
  }
}

// ---------------- O-projection GEMM (m97 core, f32 out) --------------------
__global__ __launch_bounds__(256, 3) void gemm_o(const unsigned short* __restrict__ A,
                                                 const unsigned short* __restrict__ B,
                                                 float* __restrict__ C,
                                                 int N, int K, int nbx) {
  __shared__ unsigned short As[2][128 * 32];
  __shared__ unsigned short Bs[2][128 * 32];
  GEMM97_PREAMBLE(K)

  auto stage = [&](int t, int sb) {
    int k0 = t * 32;
#pragma unroll
    for (int l = 0; l < 2; l++) {
      glds16(A + offA[l] + k0, &As[sb][(tid + l * 256) * 8]);
      glds16(B + offB[l] + k0, &Bs[sb][(tid + l * 256) * 8]);
    }
  };

  f32x4 acc[4][4];
#pragma unroll
  for (int i = 0; i < 4; i++)
#pragma unroll
    for (int j = 0; j < 4; j++) acc[i][j] = f32x4{0.f, 0.f, 0.f, 0.f};

  stage(0, 0);
  int buf = 0;
#pragma unroll 1
  for (int t = 0; t < NT; ++t) {
    __syncthreads();
    if (t + 1 < NT) stage(t + 1, buf ^ 1);
    bf16x8 af[4], bfr[4];
#pragma unroll
    for (int mf = 0; mf < 4; mf++) af[mf] = ldfrag97(As[buf], wm * 64 + mf * 16 + fr, g);
#pragma unroll
    for (int nf = 0; nf < 4; nf++) bfr[nf] = ldfrag97(Bs[buf], wn * 64 + nf * 16 + fr, g);
    __builtin_amdgcn_s_setprio(1);
#pragma unroll
    for (int mf = 0; mf < 4; mf++)
#pragma unroll
      for (int nf = 0; nf < 4; nf++)
        acc[mf][nf] = __builtin_amdgcn_mfma_f32_16x16x32_bf16(af[mf], bfr[nf], acc[mf][nf], 0, 0, 0);
    __builtin_amdgcn_s_setprio(0);
    buf ^= 1;
  }

#pragma unroll
  for (int i = 0; i < 4; i++) {
#pragma unroll
    for (int j = 0; j < 4; j++) {
      int rbase = row0 + wm * 64 + i * 16 + g * 4;
      int cb = col0 + wn * 64 + j * 16 + fr;
#pragma unroll
      for (int r = 0; r < 4; r++)
        C[(size_t)(rbase + r) * N + cb] = acc[i][j][r];
    }
  }
}

// ---------------- flash attention: block = (q-tile32, kvh, b), 8 waves ----
// KV tile = 64 as two 32-halves in adjacent LDS sub-buffers: one barrier
// pair per 64 KV (half the barrier crossings of R16). Per-half math,
// swizzle, and mask identical to the verified 32-KV step. 2 blocks/CU.
__global__ __launch_bounds__(512, 2) void attn_kernel(const unsigned short* __restrict__ qro,
                                                      const unsigned short* __restrict__ kro,
                                                      const unsigned short* __restrict__ vt,
                                                      unsigned short* __restrict__ out) {
  __shared__ unsigned short Ks[2][2][32 * 128];  // [buf][half][kv][d]
  __shared__ unsigned short Vs[2][2][64 * 64];   // [buf][half][paired-d][kv]
  const int tid = threadIdx.x, lane = tid & 63, w = tid >> 6;
  const int kvhb = blockIdx.x & 7;             // XCD pin
  const int kvh = kvhb & 3, b = kvhb >> 2;
  const int s = blockIdx.x >> 3;               // 0..63
  const int T = (s < 32) ? s : (95 - s);       // mirrored pairs {T, 63-T}
  const int sub = w >> 2, hh2 = w & 3;
  const int h = kvh * 4 + hh2;                 // wave = (head, q16-subtile)
  const int qbase = T * 32 + sub * 16;
  const int fr = lane & 15, g = lane >> 4, fk = g * 8;
  const unsigned short* Kp = kro + (size_t)(b * 4 + kvh) * 2048 * 128;
  const unsigned short* Vtp = vt + (size_t)(b * 4 + kvh) * 128 * 2048;
  const unsigned short* Qp = qro + ((size_t)(b * 16 + h) * 2048 + qbase) * 128;

  bf16x8 qf[4];
#pragma unroll
  for (int kk = 0; kk < 4; kk++)
    qf[kk] = *reinterpret_cast<const bf16x8*>(Qp + fr * 128 + kk * 32 + fk);

  u16x8 onesu;
#pragma unroll
  for (int j = 0; j < 8; j++) onesu[j] = 0x3F80;  // bf16 1.0
  bf16x8 ones = __builtin_bit_cast(bf16x8, onesu);

  f32x4 o[8];
#pragma unroll
  for (int dt = 0; dt < 8; dt++) o[dt] = f32x4{0.f, 0.f, 0.f, 0.f};
  f32x4 dacc = f32x4{0.f, 0.f, 0.f, 0.f};
  const int qrow_s = qbase + fr;
  const int niter = (T + 2) >> 1;              // 64-KV tiles; last one masked

  const int krow = w * 4 + (lane >> 4);        // K stage row (per half)
  const int kcol = lane & 15;
  const int vr = w * 8 + (lane >> 3);          // V paired-d row (per half)
  const int vcol = lane & 7;

  auto stage = [&](int kv0, int buf) {
#pragma unroll
    for (int hf = 0; hf < 2; hf++) {
      int kvh0 = kv0 + hf * 32;
      glds16(Kp + (size_t)(kvh0 + krow) * 128 + ((kcol ^ (krow & 7)) * 8),
             &Ks[buf][hf][w * 4 * 128]);
      int u = vcol ^ (vr & 7);
      int d = 2 * vr + (u >> 2);
      glds16(Vtp + (size_t)d * 2048 + kvh0 + (u & 3) * 8,
             &Vs[buf][hf][w * 8 * 64]);
    }
  };

  auto step = [&](int kv0, bool mask, int buf) {
#pragma unroll
    for (int hf = 0; hf < 2; hf++) {
      const unsigned short* Kb = &Ks[buf][hf][0];
      const unsigned short* Vb = &Vs[buf][hf][0];
      int kvh0 = kv0 + hf * 32;
      f32x4 sc[2];
      sc[0] = sc[1] = f32x4{0.f, 0.f, 0.f, 0.f};
      __builtin_amdgcn_s_setprio(1);
#pragma unroll
      for (int kk = 0; kk < 4; kk++) {
        int blk = ((kk * 4 + g) ^ (fr & 7)) * 8;
        bf16x8 ka0 = *reinterpret_cast<const bf16x8*>(Kb + (fr +  0) * 128 + blk);
        bf16x8 ka1 = *reinterpret_cast<const bf16x8*>(Kb + (fr + 16) * 128 + blk);
        sc[0] = __builtin_amdgcn_mfma_f32_16x16x32_bf16(ka0, qf[kk], sc[0], 0, 0, 0);
        sc[1] = __builtin_amdgcn_mfma_f32_16x16x32_bf16(ka1, qf[kk], sc[1], 0, 0, 0);
      }
      __builtin_amdgcn_s_setprio(0);
#pragma unroll
      for (int ss = 0; ss < 2; ss++)
#pragma unroll
        for (int r = 0; r < 4; r++) {
          float v = sc[ss][r];
          if (mask && (kvh0 + 16 * ss + 4 * g + r > qrow_s)) v = -1e30f;
          sc[ss][r] = __builtin_amdgcn_exp2f(v);
        }
      u16x8 pau;
#pragma unroll
      for (int j = 0; j < 4; j++) {
        pau[j]     = f2b(sc[0][j]);
        pau[4 + j] = f2b(sc[1][j]);
      }
      bf16x8 pa = __builtin_bit_cast(bf16x8, pau);
      dacc = __builtin_amdgcn_mfma_f32_16x16x32_bf16(pa, ones, dacc, 0, 0, 0);
      __builtin_amdgcn_s_setprio(1);
#pragma unroll
      for (int dt = 0; dt < 8; dt++) {
        int jr = dt * 8 + (fr >> 1);
        int c = ((fr & 1) * 4 + g) ^ (fr >> 1);
        bf16x8 vf = *reinterpret_cast<const bf16x8*>(Vb + jr * 64 + c * 8);
        o[dt] = __builtin_amdgcn_mfma_f32_16x16x32_bf16(pa, vf, o[dt], 0, 0, 0);
      }
      __builtin_amdgcn_s_setprio(0);
    }
  };

  stage(0, 0);
  int buf = 0;
  for (int i = 0; i < niter; i++) {
    __syncthreads();                 // tile i staged; prior reads of buf^1 done
    if (i + 1 < niter) stage((i + 1) * 64, buf ^ 1);
    step(i * 64, i == niter - 1, buf);
    buf ^= 1;
  }

#pragma unroll
  for (int r = 0; r < 4; r++) {
    float inv = 1.0f / dacc[r];
    int qrow = qbase + g * 4 + r;
    size_t rowoff = ((size_t)b * 2048 + qrow) * 2048 + (size_t)h * 128;
#pragma unroll
    for (int dt = 0; dt < 8; dt++)
      out[rowoff + dt * 16 + fr] = f2b(o[dt][r] * inv);
  }
}

// ---------------- launch ---------------------------------------------------
extern "C" void kernel_launch(void* const* d_in, const int* in_sizes, int n_in,
                              void* d_out, int out_size, void* d_ws, size_t ws_size,
                              hipStream_t stream) {
  const float* x  = (const float*)d_in[0];
  const float* wq = (const float*)d_in[1];
  const float* wk = (const float*)d_in[2];
  const float* wv = (const float*)d_in[3];
  const float* wo = (const float*)d_in[4];
  const float* freqs = (const float*)d_in[5];

  char* ws = (char*)d_ws;
  unsigned short* xb    = (unsigned short*)(ws);             // 16 MB, reused as attn out
  unsigned short* attn  = xb;
  unsigned short* wqkvb = (unsigned short*)(ws + 16777216);  // [3072][2048] bf16
  unsigned short* wob   = (unsigned short*)(ws + 29360128);
  float2*         cstab = (float2*)(ws + 37748736);          // [2048][64] cos/sin, 1 MB
  unsigned short* qro   = (unsigned short*)(ws + 62914560);
  unsigned short* kro   = (unsigned short*)(ws + 79691776);
  unsigned short* vt    = (unsigned short*)(ws + 83886080);

  float* out_o = (float*)d_out;
  float* out_k = (float*)d_out + 8388608;
  float* out_v = (float*)d_out + 10485760;

  cvt_fused<<<9728, 256, 0, stream>>>(x, wq, wk, wv, wo, freqs, xb, wqkvb, wob, cstab);

  // QKV (m97 core + fused RoPE/vt): 128x128 tiles -> 32x24 = 768 blocks = 3/CU
  gemm_qkv<<<768, 256, 0, stream>>>(xb, wqkvb, cstab, qro, kro, vt, out_k, out_v, 2048, 24);

  // attn: 64 q32-tiles x 8 (kvh,b) = 512 blocks of 8 waves, KV tile 64, 2/CU
  attn_kernel<<<512, 512, 0, stream>>>(qro, kro, vt, attn);

  // O: 128x128 tiles -> 32x16 = 512 blocks = 2/CU
  gemm_o<<<512, 256, 0, stream>>>(attn, wob, out_o, 2048, 2048, 16);
}